// Round 15
// baseline (330.554 us; speedup 1.0000x reference)
//
#include <hip/hip_runtime.h>
#include <math.h>

typedef unsigned short ushort_t;
typedef __attribute__((ext_vector_type(8))) short bf16x8;
typedef __attribute__((ext_vector_type(4))) float f32x4;
typedef __attribute__((ext_vector_type(4))) unsigned short us4;
typedef __attribute__((ext_vector_type(8))) unsigned short us8;

#define B_   4
#define S_   512
#define D_   4096
#define H_   32
#define G_   8
#define HD_  128
#define KV_  1024
#define M_   (B_ * S_)   // 2048
#define QN_  6144        // fused QKV column count

__device__ __forceinline__ float bf2f(ushort_t u) {
    union { unsigned u; float f; } x; x.u = ((unsigned)u) << 16; return x.f;
}
__device__ __forceinline__ ushort_t f2bf(float f) {
    union { float f; unsigned u; } x; x.f = f;
    unsigned r = x.u + 0x7fffu + ((x.u >> 16) & 1u);   // round-to-nearest-even
    return (ushort_t)(r >> 16);
}

typedef const __attribute__((address_space(1))) void* gptr_t;
typedef __attribute__((address_space(3))) void* ldsptr_t;

__device__ __forceinline__ void gload_lds16(const void* g, void* lds) {
    __builtin_amdgcn_global_load_lds((gptr_t)g, (ldsptr_t)lds, 16, 0, 0);
}

#define BAR() asm volatile("s_barrier" ::: "memory")

// ---------------- fp32 -> bf16 elementwise ----------------
__global__ void xconv(const float* __restrict__ x, ushort_t* __restrict__ xb, int n8)
{
    const int i = blockIdx.x * blockDim.x + threadIdx.x;
    if (i >= n8) return;
    const float4 a = *(const float4*)&x[(size_t)i * 8];
    const float4 b = *(const float4*)&x[(size_t)i * 8 + 4];
    us8 o;
    o[0] = f2bf(a.x); o[1] = f2bf(a.y); o[2] = f2bf(a.z); o[3] = f2bf(a.w);
    o[4] = f2bf(b.x); o[5] = f2bf(b.y); o[6] = f2bf(b.z); o[7] = f2bf(b.w);
    *(us8*)&xb[(size_t)i * 8] = o;
}

// ------- fused W transpose: {wq|wk|wv} [4096][N] fp32 -> Wt [6144][4096] bf16 -------
__global__ __launch_bounds__(256) void wconv_all(
    const float* __restrict__ wq, const float* __restrict__ wk,
    const float* __restrict__ wv, ushort_t* __restrict__ Wt)
{
    __shared__ float t[32][33];
    const int n0 = blockIdx.x * 32, k0 = blockIdx.y * 32;
    const float* W; int nsrc, N;
    if (n0 < 4096)      { W = wq; nsrc = n0;        N = 4096; }
    else if (n0 < 5120) { W = wk; nsrc = n0 - 4096; N = 1024; }
    else                { W = wv; nsrc = n0 - 5120; N = 1024; }
    const int tid = threadIdx.x;
    const int r = tid >> 3, c4 = (tid & 7) * 4;
    const float4 v = *(const float4*)&W[(size_t)(k0 + r) * N + nsrc + c4];
    t[r][c4 + 0] = v.x; t[r][c4 + 1] = v.y; t[r][c4 + 2] = v.z; t[r][c4 + 3] = v.w;
    __syncthreads();
    us4 o;
    o.x = f2bf(t[c4 + 0][r]);
    o.y = f2bf(t[c4 + 1][r]);
    o.z = f2bf(t[c4 + 2][r]);
    o.w = f2bf(t[c4 + 3][r]);
    *(us4*)&Wt[(size_t)(n0 + r) * D_ + k0 + c4] = o;
}

// ---------------- W [K][N] fp32 -> Wt [N][K] bf16 (single, for wo) ----------------
__global__ __launch_bounds__(256) void wconv(
    const float* __restrict__ W, ushort_t* __restrict__ Wt, int K, int N)
{
    __shared__ float t[32][33];
    const int n0 = blockIdx.x * 32, k0 = blockIdx.y * 32;
    const int tid = threadIdx.x;
    const int r = tid >> 3, c4 = (tid & 7) * 4;
    const float4 v = *(const float4*)&W[(size_t)(k0 + r) * N + n0 + c4];
    t[r][c4 + 0] = v.x; t[r][c4 + 1] = v.y; t[r][c4 + 2] = v.z; t[r][c4 + 3] = v.w;
    __syncthreads();
    us4 o;
    o.x = f2bf(t[c4 + 0][r]);
    o.y = f2bf(t[c4 + 1][r]);
    o.z = f2bf(t[c4 + 2][r]);
    o.w = f2bf(t[c4 + 3][r]);
    *(us4*)&Wt[(size_t)(n0 + r) * K + k0 + c4] = o;
}

// ============ QKV GEMM: 128x384 tiles -> grid 16x16 = 256 (round-14 proven) ============
__global__ __launch_bounds__(512, 2) void gemm_qkv(
    const ushort_t* __restrict__ A,    // [M][4096] bf16
    const ushort_t* __restrict__ Bt,   // [6144][4096] bf16
    const float* __restrict__ bias0, const float* __restrict__ bias1,
    const float* __restrict__ bias2,
    ushort_t* __restrict__ Cb)         // [M][6144] bf16
{
    __shared__ ushort_t sA[2][128 * 64];   // 32 KiB
    __shared__ ushort_t sB[2][384 * 64];   // 96 KiB

    const int tid = threadIdx.x;
    const int lane = tid & 63, w = tid >> 6;
    const int lr = lane & 15, kg = lane >> 4;
    const int wr = w >> 2, wc = w & 3;

    const int bid = (blockIdx.x & 7) * 32 + (blockIdx.x >> 3);
    const int bx = bid & 15, by = bid >> 4;
    const int bm0 = by << 7, bn0 = bx * 384;

    const int NT = 64;
    const int lda = D_, ldb = D_, N = QN_;

    const ushort_t* gp[4][2];
    char*           lp[4][2];
    #pragma unroll
    for (int u = 0; u < 4; ++u) {
        #pragma unroll
        for (int j = 0; j < 2; ++j) {
            const int o = j * 8192 + tid * 16;
            const int row = o >> 7, slot = (o >> 4) & 7;
            if (u == 0) {
                gp[u][j] = A + (size_t)(bm0 + row) * lda + ((slot ^ (row & 7)) << 3);
                lp[u][j] = (char*)sA + j * 8192 + w * 1024;
            } else {
                const int brow = (u - 1) * 128 + row;
                gp[u][j] = Bt + (size_t)(bn0 + brow) * ldb + ((slot ^ (row & 7)) << 3);
                lp[u][j] = (char*)sB + (u - 1) * 16384 + j * 8192 + w * 1024;
            }
        }
    }
    auto stage = [&](int t, int u, int c) {
        const int coff = (u == 0) ? c * 16384 : c * 49152;
        #pragma unroll
        for (int j = 0; j < 2; ++j)
            gload_lds16(gp[u][j] + t * 64, lp[u][j] + coff);
    };
    auto lda_frag = [&](int c, int mi, int s) {
        const int row = mi * 32 + wr * 16 + lr;
        return *(const bf16x8*)((const char*)sA + c * 16384 + row * 128 +
                                (((s * 4 + kg) ^ (row & 7)) << 4));
    };
    auto ldb_frag = [&](int c, int ni, int s) {
        const int row = ni * 64 + wc * 16 + lr;
        return *(const bf16x8*)((const char*)sB + c * 49152 + row * 128 +
                                (((s * 4 + kg) ^ (row & 7)) << 4));
    };

    f32x4 acc[4][6];
    #pragma unroll
    for (int i = 0; i < 4; ++i)
        #pragma unroll
        for (int j = 0; j < 6; ++j)
            acc[i][j] = (f32x4){0.f, 0.f, 0.f, 0.f};

    stage(0, 0, 0); stage(0, 1, 0); stage(0, 2, 0); stage(0, 3, 0);
    stage(1, 0, 1); stage(1, 1, 1); stage(1, 2, 1);
    asm volatile("s_waitcnt vmcnt(6)" ::: "memory");
    BAR();

    auto iter = [&](int t, int c) {
        bf16x8 a[4][2], b[2][2];

        #pragma unroll
        for (int ni = 0; ni < 2; ++ni)
            #pragma unroll
            for (int s = 0; s < 2; ++s) b[ni][s] = ldb_frag(c, ni, s);
        #pragma unroll
        for (int mi = 0; mi < 4; ++mi)
            #pragma unroll
            for (int s = 0; s < 2; ++s) a[mi][s] = lda_frag(c, mi, s);
        if (t + 1 < NT) stage(t + 1, 3, c ^ 1);
        BAR();
        __builtin_amdgcn_s_setprio(1);
        #pragma unroll
        for (int mi = 0; mi < 4; ++mi)
            #pragma unroll
            for (int ni = 0; ni < 2; ++ni)
                #pragma unroll
                for (int s = 0; s < 2; ++s)
                    acc[mi][ni] = __builtin_amdgcn_mfma_f32_16x16x32_bf16(
                        a[mi][s], b[ni][s], acc[mi][ni], 0, 0, 0);
        __builtin_amdgcn_s_setprio(0);
        BAR();

        #pragma unroll
        for (int ni = 0; ni < 2; ++ni)
            #pragma unroll
            for (int s = 0; s < 2; ++s) b[ni][s] = ldb_frag(c, ni + 2, s);
        if (t + 2 < NT) { stage(t + 2, 0, c); stage(t + 2, 1, c); }
        BAR();
        __builtin_amdgcn_s_setprio(1);
        #pragma unroll
        for (int mi = 0; mi < 4; ++mi)
            #pragma unroll
            for (int ni = 0; ni < 2; ++ni)
                #pragma unroll
                for (int s = 0; s < 2; ++s)
                    acc[mi][ni + 2] = __builtin_amdgcn_mfma_f32_16x16x32_bf16(
                        a[mi][s], b[ni][s], acc[mi][ni + 2], 0, 0, 0);
        __builtin_amdgcn_s_setprio(0);
        BAR();

        #pragma unroll
        for (int ni = 0; ni < 2; ++ni)
            #pragma unroll
            for (int s = 0; s < 2; ++s) b[ni][s] = ldb_frag(c, ni + 4, s);
        if (t + 2 < NT) {
            stage(t + 2, 2, c);
            asm volatile("s_waitcnt vmcnt(6)" ::: "memory");
        } else {
            asm volatile("s_waitcnt vmcnt(0)" ::: "memory");
        }
        BAR();
        __builtin_amdgcn_s_setprio(1);
        #pragma unroll
        for (int mi = 0; mi < 4; ++mi)
            #pragma unroll
            for (int ni = 0; ni < 2; ++ni)
                #pragma unroll
                for (int s = 0; s < 2; ++s)
                    acc[mi][ni + 4] = __builtin_amdgcn_mfma_f32_16x16x32_bf16(
                        a[mi][s], b[ni][s], acc[mi][ni + 4], 0, 0, 0);
        __builtin_amdgcn_s_setprio(0);
        BAR();
    };

    for (int t = 0; t < NT; t += 2) { iter(t, 0); iter(t + 1, 1); }

    // ---- epilogue: bias + per-pair RoPE (q: rope*1/128, k: rope, v: plain) ----
    const int jj = wc * 16 + lr;
    const float invf = __expf(-0.1439115683121279f * (float)jj); // 10000^(-jj/64)
    #pragma unroll
    for (int mi = 0; mi < 4; ++mi) {
        const int mr = bm0 + mi * 32 + wr * 16 + kg * 4;
        #pragma unroll
        for (int r = 0; r < 4; ++r) {
            const int srow = (mr + r) & 511;
            float sn, cs;
            __sincosf((float)srow * invf, &sn, &cs);
            #pragma unroll
            for (int nip = 0; nip < 3; ++nip) {
                const int pb = bn0 + nip * 128;
                const int n_lo = pb + jj, n_hi = n_lo + 64;
                const float b_lo = (n_lo < 4096) ? bias0[n_lo]
                                 : (n_lo < 5120) ? bias1[n_lo - 4096] : bias2[n_lo - 5120];
                const float b_hi = (n_hi < 4096) ? bias0[n_hi]
                                 : (n_hi < 5120) ? bias1[n_hi - 4096] : bias2[n_hi - 5120];
                const float a_lo = acc[mi][nip * 2][r] + b_lo;
                const float a_hi = acc[mi][nip * 2 + 1][r] + b_hi;
                if (pb < 5120) {
                    const float scale = (pb < 4096) ? (1.f / 128.f) : 1.f;
                    Cb[(size_t)(mr + r) * N + n_lo] = f2bf((a_lo * cs - a_hi * sn) * scale);
                    Cb[(size_t)(mr + r) * N + n_hi] = f2bf((a_hi * cs + a_lo * sn) * scale);
                } else {
                    Cb[(size_t)(mr + r) * N + n_lo] = f2bf(a_lo);
                    Cb[(size_t)(mr + r) * N + n_hi] = f2bf(a_hi);
                }
            }
        }
    }
}

// ============ 256x256 8-phase MFMA GEMM, O-proj split-K=2 with atomic merge ============
// Both K-halves atomicAdd into Cf (pre-zeroed by hipMemsetAsync): khalf0 adds
// acc+bias, khalf1 adds raw acc.  Exactly 2 contributions per element; IEEE
// fp32 add is commutative -> fl(a+b) == fl(b+a) -> bit-deterministic.
// (Split-K>2 would need associativity -> nondeterministic; stay at 2.)
__global__ __launch_bounds__(512, 2) void gemm8_oproj(
    const ushort_t* __restrict__ A, int lda,
    const ushort_t* __restrict__ Bt, int ldb,
    const float* __restrict__ bias0,
    float* __restrict__ Cf,
    int M, int N, int K)
{
    __shared__ ushort_t sA[2][256 * 64];   // 64 KiB
    __shared__ ushort_t sB[2][256 * 64];   // 64 KiB

    const int tid = threadIdx.x;
    const int lane = tid & 63, w = tid >> 6;
    const int lr = lane & 15, kg = lane >> 4;
    const int wr = w >> 2, wc = w & 3;

    const int nwg = gridDim.x;
    const int cpx = nwg >> 3;
    const int bid = (blockIdx.x & 7) * cpx + (blockIdx.x >> 3);
    const int khalf = bid >> 7, tile = bid & 127;
    const int nbx = N >> 8;
    const int bx = tile % nbx, by = tile / nbx;
    const int bm0 = by << 8, bn0 = bx << 8;
    A += (size_t)khalf * K; Bt += (size_t)khalf * K;

    const int NT = K >> 6;

    const ushort_t* gp[4][2];
    char*           lp[4][2];
    #pragma unroll
    for (int h = 0; h < 4; ++h) {
        const ushort_t* gb; int ld; char* sbase;
        if (h < 2) { gb = A + (size_t)bm0 * lda; ld = lda; sbase = (char*)sA; }
        else       { gb = Bt + (size_t)bn0 * ldb; ld = ldb; sbase = (char*)sB; }
        const int half = h & 1;
        #pragma unroll
        for (int j = 0; j < 2; ++j) {
            const int o = j * 8192 + tid * 16;
            const int row = half * 128 + (o >> 7);
            const int slot = (o >> 4) & 7;
            gp[h][j] = gb + (size_t)row * ld + ((slot ^ (row & 7)) << 3);
            lp[h][j] = sbase + half * 16384 + j * 8192 + w * 1024;
        }
    }
    auto stage = [&](int t, int h, int c) {
        #pragma unroll
        for (int j = 0; j < 2; ++j)
            gload_lds16(gp[h][j] + t * 64, lp[h][j] + c * 32768);
    };
    auto lda_frag = [&](int c, int mi, int s) {
        const int row = mi * 32 + wr * 16 + lr;
        return *(const bf16x8*)((const char*)sA + c * 32768 + row * 128 +
                                (((s * 4 + kg) ^ (row & 7)) << 4));
    };
    auto ldb_frag = [&](int c, int ni, int s) {
        const int row = ni * 64 + wc * 16 + lr;
        return *(const bf16x8*)((const char*)sB + c * 32768 + row * 128 +
                                (((s * 4 + kg) ^ (row & 7)) << 4));
    };

    f32x4 acc[8][4];
    #pragma unroll
    for (int i = 0; i < 8; ++i)
        #pragma unroll
        for (int j = 0; j < 4; ++j)
            acc[i][j] = (f32x4){0.f, 0.f, 0.f, 0.f};

    stage(0, 0, 0); stage(0, 2, 0); stage(0, 3, 0); stage(0, 1, 0);
    stage(1, 0, 1); stage(1, 2, 1); stage(1, 3, 1);
    asm volatile("s_waitcnt vmcnt(6)" ::: "memory");
    BAR();

    auto iter = [&](int t, int c) {
        bf16x8 a[4][2], b[4][2];

        #pragma unroll
        for (int ni = 0; ni < 2; ++ni)
            #pragma unroll
            for (int s = 0; s < 2; ++s) b[ni][s] = ldb_frag(c, ni, s);
        #pragma unroll
        for (int mi = 0; mi < 4; ++mi)
            #pragma unroll
            for (int s = 0; s < 2; ++s) a[mi][s] = lda_frag(c, mi, s);
        if (t + 1 < NT) stage(t + 1, 1, c ^ 1);
        BAR();
        __builtin_amdgcn_s_setprio(1);
        #pragma unroll
        for (int mi = 0; mi < 4; ++mi)
            #pragma unroll
            for (int ni = 0; ni < 2; ++ni)
                #pragma unroll
                for (int s = 0; s < 2; ++s)
                    acc[mi][ni] = __builtin_amdgcn_mfma_f32_16x16x32_bf16(
                        a[mi][s], b[ni][s], acc[mi][ni], 0, 0, 0);
        __builtin_amdgcn_s_setprio(0);
        BAR();

        #pragma unroll
        for (int ni = 2; ni < 4; ++ni)
            #pragma unroll
            for (int s = 0; s < 2; ++s) b[ni][s] = ldb_frag(c, ni, s);
        if (t + 2 < NT) stage(t + 2, 0, c);
        BAR();
        __builtin_amdgcn_s_setprio(1);
        #pragma unroll
        for (int mi = 0; mi < 4; ++mi)
            #pragma unroll
            for (int ni = 2; ni < 4; ++ni)
                #pragma unroll
                for (int s = 0; s < 2; ++s)
                    acc[mi][ni] = __builtin_amdgcn_mfma_f32_16x16x32_bf16(
                        a[mi][s], b[ni][s], acc[mi][ni], 0, 0, 0);
        __builtin_amdgcn_s_setprio(0);
        BAR();

        #pragma unroll
        for (int mi = 0; mi < 4; ++mi)
            #pragma unroll
            for (int s = 0; s < 2; ++s) a[mi][s] = lda_frag(c, mi + 4, s);
        if (t + 2 < NT) stage(t + 2, 2, c);
        BAR();
        __builtin_amdgcn_s_setprio(1);
        #pragma unroll
        for (int mi = 0; mi < 4; ++mi)
            #pragma unroll
            for (int ni = 2; ni < 4; ++ni)
                #pragma unroll
                for (int s = 0; s < 2; ++s)
                    acc[mi + 4][ni] = __builtin_amdgcn_mfma_f32_16x16x32_bf16(
                        a[mi][s], b[ni][s], acc[mi + 4][ni], 0, 0, 0);
        __builtin_amdgcn_s_setprio(0);
        BAR();

        if (t + 2 < NT) {
            stage(t + 2, 3, c);
            asm volatile("s_waitcnt vmcnt(6)" ::: "memory");
        } else {
            asm volatile("s_waitcnt vmcnt(0)" ::: "memory");
        }
        BAR();
        __builtin_amdgcn_s_setprio(1);
        #pragma unroll
        for (int mi = 0; mi < 4; ++mi)
            #pragma unroll
            for (int ni = 0; ni < 2; ++ni)
                #pragma unroll
                for (int s = 0; s < 2; ++s)
                    acc[mi + 4][ni] = __builtin_amdgcn_mfma_f32_16x16x32_bf16(
                        a[mi][s], b[ni][s], acc[mi + 4][ni], 0, 0, 0);
        __builtin_amdgcn_s_setprio(0);
        BAR();
    };

    for (int t = 0; t < NT; t += 2) { iter(t, 0); iter(t + 1, 1); }

    // ---- epilogue: atomic merge into pre-zeroed out ----
    #pragma unroll
    for (int mi = 0; mi < 8; ++mi) {
        #pragma unroll
        for (int ni = 0; ni < 4; ++ni) {
            const int n = bn0 + ni * 64 + wc * 16 + lr;
            const float bs = (khalf == 0) ? bias0[n] : 0.f;
            const int mr = bm0 + mi * 32 + wr * 16 + kg * 4;
            #pragma unroll
            for (int r = 0; r < 4; ++r)
                atomicAdd(&Cf[(size_t)(mr + r) * N + n], acc[mi][ni][r] + bs);
        }
    }
}

// ---------------- V transpose: qkv v-cols -> [B*G][HD][S] ----------------
__global__ __launch_bounds__(256) void vtrans(
    const ushort_t* __restrict__ vb,   // qkv + 5120
    ushort_t* __restrict__ vT)
{
    __shared__ ushort_t t[32][40];
    const int s0 = blockIdx.x * 32;
    const int d0 = blockIdx.y * 32;
    const int bg = blockIdx.z;
    const int b = bg >> 3, g = bg & 7;
    const int tid = threadIdx.x;
    const int row = tid >> 3, c4 = (tid & 7) * 4;
    const us4 v = *(const us4*)&vb[(size_t)(b * S_ + s0 + row) * QN_ + g * HD_ + d0 + c4];
    t[row][c4 + 0] = v.x; t[row][c4 + 1] = v.y;
    t[row][c4 + 2] = v.z; t[row][c4 + 3] = v.w;
    __syncthreads();
    us4 o;
    o.x = t[c4 + 0][row]; o.y = t[c4 + 1][row];
    o.z = t[c4 + 2][row]; o.w = t[c4 + 3][row];
    *(us4*)&vT[(size_t)(bg * HD_ + d0 + row) * S_ + s0 + c4] = o;
}

// ---------------- MFMA attention: block = (b, h, 64 q-rows), 4 waves ----------------
__global__ __launch_bounds__(256) void attn_mfma(
    const ushort_t* __restrict__ kb,   // qkv + 4096 (rope'd K cols)
    const ushort_t* __restrict__ vT,   // [B*G][HD][S]
    ushort_t* __restrict__ qb)         // qkv (rope'd+scaled q cols), in/out
{
    __shared__ ushort_t sKV[8192];          // 16 KB staging
    __shared__ ushort_t sP[4 * 16 * 512];   // 64 KB per-wave P

    const int q0 = blockIdx.x * 64;
    const int h = blockIdx.y, b = blockIdx.z;
    const int g = h >> 2;
    const int tid = threadIdx.x;
    const int lane = tid & 63, w = tid >> 6;
    const int lr = lane & 15, kg = lane >> 4;

    bf16x8 af[4];
    {
        const ushort_t* qrow = qb + (size_t)(b * S_ + q0 + w * 16 + lr) * QN_ + h * HD_;
        #pragma unroll
        for (int c = 0; c < 4; ++c)
            af[c] = *(const bf16x8*)(qrow + c * 32 + kg * 8);
    }

    f32x4 l[8][4];
    #pragma unroll
    for (int ch = 0; ch < 8; ++ch)
        #pragma unroll
        for (int t = 0; t < 4; ++t)
            l[ch][t] = (f32x4){0.f, 0.f, 0.f, 0.f};

    // ---- QK^T ----
    const ushort_t* kbase = kb + (size_t)b * S_ * QN_ + g * HD_;
    #pragma unroll
    for (int ch = 0; ch < 8; ++ch) {
        __syncthreads();
        #pragma unroll
        for (int i = 0; i < 4; ++i) {
            const int o = w * 4096 + i * 1024;
            const int key = (o >> 8) + (lane >> 4);
            const int sl = lane & 15;
            gload_lds16(kbase + (size_t)(ch * 64 + key) * QN_ + ((sl ^ (key & 15)) * 8),
                        (char*)sKV + o);
        }
        __syncthreads();
        #pragma unroll
        for (int t = 0; t < 4; ++t) {
            const int key = t * 16 + lr;
            #pragma unroll
            for (int c = 0; c < 4; ++c) {
                const bf16x8 bf = *(const bf16x8*)((const char*)sKV + key * 256 +
                                                   (((c * 4 + kg) ^ (key & 15)) << 4));
                l[ch][t] = __builtin_amdgcn_mfma_f32_16x16x32_bf16(af[c], bf, l[ch][t], 0, 0, 0);
            }
        }
    }

    // ---- softmax ----
    float inv[4];
    #pragma unroll
    for (int r = 0; r < 4; ++r) {
        float m = -1e30f;
        #pragma unroll
        for (int ch = 0; ch < 8; ++ch)
            #pragma unroll
            for (int t = 0; t < 4; ++t)
                m = fmaxf(m, l[ch][t][r]);
        #pragma unroll
        for (int msk = 1; msk <= 8; msk <<= 1)
            m = fmaxf(m, __shfl_xor(m, msk));
        float s = 0.f;
        const int q = kg * 4 + r;
        #pragma unroll
        for (int ch = 0; ch < 8; ++ch)
            #pragma unroll
            for (int t = 0; t < 4; ++t) {
                const float p = __expf(l[ch][t][r] - m);
                s += p;
                const int gs = ch * 8 + t * 2 + (lr >> 3);
                sP[w * 8192 + q * 512 + ((gs ^ q) << 3) + (lr & 7)] = f2bf(p);
            }
        #pragma unroll
        for (int msk = 1; msk <= 8; msk <<= 1)
            s += __shfl_xor(s, msk);
        inv[r] = 1.f / s;
    }

    // ---- PV ----
    f32x4 oacc[8];
    #pragma unroll
    for (int dt = 0; dt < 8; ++dt) oacc[dt] = (f32x4){0.f, 0.f, 0.f, 0.f};

    const ushort_t* vbase = vT + (size_t)(b * G_ + g) * HD_ * S_;
    for (int ch = 0; ch < 8; ++ch) {
        __syncthreads();
        #pragma unroll
        for (int i = 0; i < 4; ++i) {
            const int o = w * 4096 + i * 1024;
            const int d = (o >> 7) + (lane >> 3);
            const int sl = lane & 7;
            gload_lds16(vbase + (size_t)d * S_ + ch * 64 + ((sl ^ (d & 7)) * 8),
                        (char*)sKV + o);
        }
        __syncthreads();
        #pragma unroll
        for (int c2 = 0; c2 < 2; ++c2) {
            const int gs = ch * 8 + c2 * 4 + kg;
            const bf16x8 ap = *(const bf16x8*)((const char*)sP + w * 16384 + lr * 1024 +
                                               ((gs ^ lr) << 4));
            #pragma unroll
            for (int dt = 0; dt < 8; ++dt) {
                const int d = dt * 16 + lr;
                const bf16x8 bv = *(const bf16x8*)((const char*)sKV + d * 128 +
                                                   (((c2 * 4 + kg) ^ (d & 7)) << 4));
                oacc[dt] = __builtin_amdgcn_mfma_f32_16x16x32_bf16(ap, bv, oacc[dt], 0, 0, 0);
            }
        }
    }

    #pragma unroll
    for (int dt = 0; dt < 8; ++dt) {
        #pragma unroll
        for (int r = 0; r < 4; ++r) {
            const int q = kg * 4 + r;
            qb[(size_t)(b * S_ + q0 + w * 16 + q) * QN_ + h * HD_ + dt * 16 + lr] =
                f2bf(oacc[dt][r] * inv[r]);
        }
    }
}

extern "C" void kernel_launch(void* const* d_in, const int* in_sizes, int n_in,
                              void* d_out, int out_size, void* d_ws, size_t ws_size,
                              hipStream_t stream)
{
    const float* x  = (const float*)d_in[0];
    const float* wq = (const float*)d_in[1];
    const float* bq = (const float*)d_in[2];
    const float* wk = (const float*)d_in[3];
    const float* bk = (const float*)d_in[4];
    const float* wv = (const float*)d_in[5];
    const float* bv = (const float*)d_in[6];
    const float* wo = (const float*)d_in[7];
    const float* bo = (const float*)d_in[8];
    float* out = (float*)d_out;

    char* ws = (char*)d_ws;
    ushort_t* xb   = (ushort_t*)(ws);                 // 16 MB: x bf16
    ushort_t* Wt   = (ushort_t*)(ws + (16u << 20));   // 48 MB: wq|wk|wv; later wo rows 0-4095
    ushort_t* vT   = (ushort_t*)(ws + (48u << 20));   //  4 MB: dead wk rows after QKV GEMM
    ushort_t* qkv  = (ushort_t*)(ws + (64u << 20));   // 24 MB: [2048][6144] bf16
    // total 88 MB

    // zero out early (atomic O-proj accumulates into it)
    hipMemsetAsync(out, 0, (size_t)M_ * D_ * sizeof(float), stream);

    // weights first, x last -> QKV GEMM inputs are the freshest L3 stream
    wconv_all<<<dim3(QN_ / 32, D_ / 32), 256, 0, stream>>>(wq, wk, wv, Wt);
    xconv<<<(M_ * D_ / 8 + 255) / 256, 256, 0, stream>>>(x, xb, M_ * D_ / 8);

    // fused QKV projection + RoPE + q-scale, 128x384 tiles, full 256-block fill
    gemm_qkv<<<256, 512, 0, stream>>>(xb, Wt, bq, bk, bv, qkv);

    vtrans<<<dim3(S_ / 32, HD_ / 32, B_ * G_), 256, 0, stream>>>(qkv + 5120, vT);

    attn_mfma<<<dim3(S_ / 64, H_, B_), 256, 0, stream>>>(qkv + 4096, vT, qkv);

    // wo -> rows 0-4095 of Wt (wq part is dead now)
    wconv<<<dim3(D_ / 32, D_ / 32), 256, 0, stream>>>(wo, Wt, D_, D_);

    // O projection, split-K=2, atomic merge into pre-zeroed out
    gemm8_oproj<<<256, 512, 0, stream>>>(qkv, QN_, Wt, D_, bo, out, M_, D_, 2048);
}

// Round 16
// 310.785 us; speedup vs baseline: 1.0636x; 1.0636x over previous
//
#include <hip/hip_runtime.h>
#include <math.h>

typedef unsigned short ushort_t;
typedef __attribute__((ext_vector_type(8))) short bf16x8;
typedef __attribute__((ext_vector_type(4))) float f32x4;
typedef __attribute__((ext_vector_type(4))) unsigned short us4;
typedef __attribute__((ext_vector_type(8))) unsigned short us8;

#define B_   4
#define S_   512
#define D_   4096
#define H_   32
#define G_   8
#define HD_  128
#define KV_  1024
#define M_   (B_ * S_)   // 2048
#define QN_  6144        // fused QKV column count

__device__ __forceinline__ float bf2f(ushort_t u) {
    union { unsigned u; float f; } x; x.u = ((unsigned)u) << 16; return x.f;
}
__device__ __forceinline__ ushort_t f2bf(float f) {
    union { float f; unsigned u; } x; x.f = f;
    unsigned r = x.u + 0x7fffu + ((x.u >> 16) & 1u);   // round-to-nearest-even
    return (ushort_t)(r >> 16);
}

typedef const __attribute__((address_space(1))) void* gptr_t;
typedef __attribute__((address_space(3))) void* ldsptr_t;

__device__ __forceinline__ void gload_lds16(const void* g, void* lds) {
    __builtin_amdgcn_global_load_lds((gptr_t)g, (ldsptr_t)lds, 16, 0, 0);
}

#define BAR() asm volatile("s_barrier" ::: "memory")

// ---------------- fp32 -> bf16 elementwise ----------------
__global__ void xconv(const float* __restrict__ x, ushort_t* __restrict__ xb, int n8)
{
    const int i = blockIdx.x * blockDim.x + threadIdx.x;
    if (i >= n8) return;
    const float4 a = *(const float4*)&x[(size_t)i * 8];
    const float4 b = *(const float4*)&x[(size_t)i * 8 + 4];
    us8 o;
    o[0] = f2bf(a.x); o[1] = f2bf(a.y); o[2] = f2bf(a.z); o[3] = f2bf(a.w);
    o[4] = f2bf(b.x); o[5] = f2bf(b.y); o[6] = f2bf(b.z); o[7] = f2bf(b.w);
    *(us8*)&xb[(size_t)i * 8] = o;
}

// ------- fused W transpose: {wq|wk|wv} [4096][N] fp32 -> Wt [6144][4096] bf16 -------
__global__ __launch_bounds__(256) void wconv_all(
    const float* __restrict__ wq, const float* __restrict__ wk,
    const float* __restrict__ wv, ushort_t* __restrict__ Wt)
{
    __shared__ float t[32][33];
    const int n0 = blockIdx.x * 32, k0 = blockIdx.y * 32;
    const float* W; int nsrc, N;
    if (n0 < 4096)      { W = wq; nsrc = n0;        N = 4096; }
    else if (n0 < 5120) { W = wk; nsrc = n0 - 4096; N = 1024; }
    else                { W = wv; nsrc = n0 - 5120; N = 1024; }
    const int tid = threadIdx.x;
    const int r = tid >> 3, c4 = (tid & 7) * 4;
    const float4 v = *(const float4*)&W[(size_t)(k0 + r) * N + nsrc + c4];
    t[r][c4 + 0] = v.x; t[r][c4 + 1] = v.y; t[r][c4 + 2] = v.z; t[r][c4 + 3] = v.w;
    __syncthreads();
    us4 o;
    o.x = f2bf(t[c4 + 0][r]);
    o.y = f2bf(t[c4 + 1][r]);
    o.z = f2bf(t[c4 + 2][r]);
    o.w = f2bf(t[c4 + 3][r]);
    *(us4*)&Wt[(size_t)(n0 + r) * D_ + k0 + c4] = o;
}

// ---------------- W [K][N] fp32 -> Wt [N][K] bf16 (single, for wo) ----------------
__global__ __launch_bounds__(256) void wconv(
    const float* __restrict__ W, ushort_t* __restrict__ Wt, int K, int N)
{
    __shared__ float t[32][33];
    const int n0 = blockIdx.x * 32, k0 = blockIdx.y * 32;
    const int tid = threadIdx.x;
    const int r = tid >> 3, c4 = (tid & 7) * 4;
    const float4 v = *(const float4*)&W[(size_t)(k0 + r) * N + n0 + c4];
    t[r][c4 + 0] = v.x; t[r][c4 + 1] = v.y; t[r][c4 + 2] = v.z; t[r][c4 + 3] = v.w;
    __syncthreads();
    us4 o;
    o.x = f2bf(t[c4 + 0][r]);
    o.y = f2bf(t[c4 + 1][r]);
    o.z = f2bf(t[c4 + 2][r]);
    o.w = f2bf(t[c4 + 3][r]);
    *(us4*)&Wt[(size_t)(n0 + r) * K + k0 + c4] = o;
}

// ============ QKV GEMM: 128x384 tiles -> grid 16x16 = 256 (FULL chip fill) ============
// qkv[M][6144] = xb[M][4096] @ Wt[6144][4096]^T + bias, + RoPE in epilogue.
// 8 waves (2M x 4N), per-wave C = 64x96 (4x6 frags), 48 MFMA/tile in 3 phases.
// Ledger: P1 stages B2(t+1); P2 stages A,B0(t+2); P3 stages B1(t+2)+vmcnt(6)
// (retires through B2(t+1) -> tile t+1 landed before its P1).
__global__ __launch_bounds__(512, 2) void gemm_qkv(
    const ushort_t* __restrict__ A,    // [M][4096] bf16
    const ushort_t* __restrict__ Bt,   // [6144][4096] bf16
    const float* __restrict__ bias0, const float* __restrict__ bias1,
    const float* __restrict__ bias2,
    ushort_t* __restrict__ Cb)         // [M][6144] bf16
{
    __shared__ ushort_t sA[2][128 * 64];   // 32 KiB
    __shared__ ushort_t sB[2][384 * 64];   // 96 KiB

    const int tid = threadIdx.x;
    const int lane = tid & 63, w = tid >> 6;
    const int lr = lane & 15, kg = lane >> 4;
    const int wr = w >> 2, wc = w & 3;

    const int bid = (blockIdx.x & 7) * 32 + (blockIdx.x >> 3);
    const int bx = bid & 15, by = bid >> 4;
    const int bm0 = by << 7, bn0 = bx * 384;

    const int NT = 64;
    const int lda = D_, ldb = D_, N = QN_;

    const ushort_t* gp[4][2];
    char*           lp[4][2];
    #pragma unroll
    for (int u = 0; u < 4; ++u) {
        #pragma unroll
        for (int j = 0; j < 2; ++j) {
            const int o = j * 8192 + tid * 16;
            const int row = o >> 7, slot = (o >> 4) & 7;
            if (u == 0) {
                gp[u][j] = A + (size_t)(bm0 + row) * lda + ((slot ^ (row & 7)) << 3);
                lp[u][j] = (char*)sA + j * 8192 + w * 1024;
            } else {
                const int brow = (u - 1) * 128 + row;
                gp[u][j] = Bt + (size_t)(bn0 + brow) * ldb + ((slot ^ (row & 7)) << 3);
                lp[u][j] = (char*)sB + (u - 1) * 16384 + j * 8192 + w * 1024;
            }
        }
    }
    auto stage = [&](int t, int u, int c) {
        const int coff = (u == 0) ? c * 16384 : c * 49152;
        #pragma unroll
        for (int j = 0; j < 2; ++j)
            gload_lds16(gp[u][j] + t * 64, lp[u][j] + coff);
    };
    auto lda_frag = [&](int c, int mi, int s) {
        const int row = mi * 32 + wr * 16 + lr;
        return *(const bf16x8*)((const char*)sA + c * 16384 + row * 128 +
                                (((s * 4 + kg) ^ (row & 7)) << 4));
    };
    auto ldb_frag = [&](int c, int ni, int s) {
        const int row = ni * 64 + wc * 16 + lr;
        return *(const bf16x8*)((const char*)sB + c * 49152 + row * 128 +
                                (((s * 4 + kg) ^ (row & 7)) << 4));
    };

    f32x4 acc[4][6];
    #pragma unroll
    for (int i = 0; i < 4; ++i)
        #pragma unroll
        for (int j = 0; j < 6; ++j)
            acc[i][j] = (f32x4){0.f, 0.f, 0.f, 0.f};

    stage(0, 0, 0); stage(0, 1, 0); stage(0, 2, 0); stage(0, 3, 0);
    stage(1, 0, 1); stage(1, 1, 1); stage(1, 2, 1);
    asm volatile("s_waitcnt vmcnt(6)" ::: "memory");
    BAR();

    auto iter = [&](int t, int c) {
        bf16x8 a[4][2], b[2][2];

        #pragma unroll
        for (int ni = 0; ni < 2; ++ni)
            #pragma unroll
            for (int s = 0; s < 2; ++s) b[ni][s] = ldb_frag(c, ni, s);
        #pragma unroll
        for (int mi = 0; mi < 4; ++mi)
            #pragma unroll
            for (int s = 0; s < 2; ++s) a[mi][s] = lda_frag(c, mi, s);
        if (t + 1 < NT) stage(t + 1, 3, c ^ 1);
        BAR();
        __builtin_amdgcn_s_setprio(1);
        #pragma unroll
        for (int mi = 0; mi < 4; ++mi)
            #pragma unroll
            for (int ni = 0; ni < 2; ++ni)
                #pragma unroll
                for (int s = 0; s < 2; ++s)
                    acc[mi][ni] = __builtin_amdgcn_mfma_f32_16x16x32_bf16(
                        a[mi][s], b[ni][s], acc[mi][ni], 0, 0, 0);
        __builtin_amdgcn_s_setprio(0);
        BAR();

        #pragma unroll
        for (int ni = 0; ni < 2; ++ni)
            #pragma unroll
            for (int s = 0; s < 2; ++s) b[ni][s] = ldb_frag(c, ni + 2, s);
        if (t + 2 < NT) { stage(t + 2, 0, c); stage(t + 2, 1, c); }
        BAR();
        __builtin_amdgcn_s_setprio(1);
        #pragma unroll
        for (int mi = 0; mi < 4; ++mi)
            #pragma unroll
            for (int ni = 0; ni < 2; ++ni)
                #pragma unroll
                for (int s = 0; s < 2; ++s)
                    acc[mi][ni + 2] = __builtin_amdgcn_mfma_f32_16x16x32_bf16(
                        a[mi][s], b[ni][s], acc[mi][ni + 2], 0, 0, 0);
        __builtin_amdgcn_s_setprio(0);
        BAR();

        #pragma unroll
        for (int ni = 0; ni < 2; ++ni)
            #pragma unroll
            for (int s = 0; s < 2; ++s) b[ni][s] = ldb_frag(c, ni + 4, s);
        if (t + 2 < NT) {
            stage(t + 2, 2, c);
            asm volatile("s_waitcnt vmcnt(6)" ::: "memory");
        } else {
            asm volatile("s_waitcnt vmcnt(0)" ::: "memory");
        }
        BAR();
        __builtin_amdgcn_s_setprio(1);
        #pragma unroll
        for (int mi = 0; mi < 4; ++mi)
            #pragma unroll
            for (int ni = 0; ni < 2; ++ni)
                #pragma unroll
                for (int s = 0; s < 2; ++s)
                    acc[mi][ni + 4] = __builtin_amdgcn_mfma_f32_16x16x32_bf16(
                        a[mi][s], b[ni][s], acc[mi][ni + 4], 0, 0, 0);
        __builtin_amdgcn_s_setprio(0);
        BAR();
    };

    for (int t = 0; t < NT; t += 2) { iter(t, 0); iter(t + 1, 1); }

    // ---- epilogue: bias + per-pair RoPE (q: rope*1/128, k: rope, v: plain) ----
    const int jj = wc * 16 + lr;
    const float invf = __expf(-0.1439115683121279f * (float)jj); // 10000^(-jj/64)
    #pragma unroll
    for (int mi = 0; mi < 4; ++mi) {
        const int mr = bm0 + mi * 32 + wr * 16 + kg * 4;
        #pragma unroll
        for (int r = 0; r < 4; ++r) {
            const int srow = (mr + r) & 511;
            float sn, cs;
            __sincosf((float)srow * invf, &sn, &cs);
            #pragma unroll
            for (int nip = 0; nip < 3; ++nip) {
                const int pb = bn0 + nip * 128;
                const int n_lo = pb + jj, n_hi = n_lo + 64;
                const float b_lo = (n_lo < 4096) ? bias0[n_lo]
                                 : (n_lo < 5120) ? bias1[n_lo - 4096] : bias2[n_lo - 5120];
                const float b_hi = (n_hi < 4096) ? bias0[n_hi]
                                 : (n_hi < 5120) ? bias1[n_hi - 4096] : bias2[n_hi - 5120];
                const float a_lo = acc[mi][nip * 2][r] + b_lo;
                const float a_hi = acc[mi][nip * 2 + 1][r] + b_hi;
                if (pb < 5120) {
                    const float scale = (pb < 4096) ? (1.f / 128.f) : 1.f;
                    Cb[(size_t)(mr + r) * N + n_lo] = f2bf((a_lo * cs - a_hi * sn) * scale);
                    Cb[(size_t)(mr + r) * N + n_hi] = f2bf((a_hi * cs + a_lo * sn) * scale);
                } else {
                    Cb[(size_t)(mr + r) * N + n_lo] = f2bf(a_lo);
                    Cb[(size_t)(mr + r) * N + n_hi] = f2bf(a_hi);
                }
            }
        }
    }
}

// ============ 256x256 8-phase MFMA GEMM (round-12 proven form, O-proj) ============
template<int OUT_BF16, int SPLITK, int ROPE>
__global__ __launch_bounds__(512, 2) void gemm8(
    const ushort_t* __restrict__ A, int lda,
    const ushort_t* __restrict__ Bt, int ldb,
    const float* __restrict__ bias0, const float* __restrict__ bias1,
    const float* __restrict__ bias2,
    float* __restrict__ Cf, ushort_t* __restrict__ Cb,
    float* __restrict__ P0, float* __restrict__ P1,
    int M, int N, int K)
{
    __shared__ ushort_t sA[2][256 * 64];   // 64 KiB
    __shared__ ushort_t sB[2][256 * 64];   // 64 KiB

    const int tid = threadIdx.x;
    const int lane = tid & 63, w = tid >> 6;
    const int lr = lane & 15, kg = lane >> 4;
    const int wr = w >> 2, wc = w & 3;

    const int nwg = gridDim.x;
    const int cpx = nwg >> 3;
    const int bid = (blockIdx.x & 7) * cpx + (blockIdx.x >> 3);
    int khalf = 0, tile = bid;
    if (SPLITK) { khalf = bid >> 7; tile = bid & 127; }
    const int nbx = N >> 8;
    const int bx = tile % nbx, by = tile / nbx;
    const int bm0 = by << 8, bn0 = bx << 8;
    if (SPLITK) { A += (size_t)khalf * K; Bt += (size_t)khalf * K; }

    const int NT = K >> 6;

    const ushort_t* gp[4][2];
    char*           lp[4][2];
    #pragma unroll
    for (int h = 0; h < 4; ++h) {
        const ushort_t* gb; int ld; char* sbase;
        if (h < 2) { gb = A + (size_t)bm0 * lda; ld = lda; sbase = (char*)sA; }
        else       { gb = Bt + (size_t)bn0 * ldb; ld = ldb; sbase = (char*)sB; }
        const int half = h & 1;
        #pragma unroll
        for (int j = 0; j < 2; ++j) {
            const int o = j * 8192 + tid * 16;
            const int row = half * 128 + (o >> 7);
            const int slot = (o >> 4) & 7;
            gp[h][j] = gb + (size_t)row * ld + ((slot ^ (row & 7)) << 3);
            lp[h][j] = sbase + half * 16384 + j * 8192 + w * 1024;
        }
    }
    auto stage = [&](int t, int h, int c) {
        #pragma unroll
        for (int j = 0; j < 2; ++j)
            gload_lds16(gp[h][j] + t * 64, lp[h][j] + c * 32768);
    };
    auto lda_frag = [&](int c, int mi, int s) {
        const int row = mi * 32 + wr * 16 + lr;
        return *(const bf16x8*)((const char*)sA + c * 32768 + row * 128 +
                                (((s * 4 + kg) ^ (row & 7)) << 4));
    };
    auto ldb_frag = [&](int c, int ni, int s) {
        const int row = ni * 64 + wc * 16 + lr;
        return *(const bf16x8*)((const char*)sB + c * 32768 + row * 128 +
                                (((s * 4 + kg) ^ (row & 7)) << 4));
    };

    f32x4 acc[8][4];
    #pragma unroll
    for (int i = 0; i < 8; ++i)
        #pragma unroll
        for (int j = 0; j < 4; ++j)
            acc[i][j] = (f32x4){0.f, 0.f, 0.f, 0.f};

    stage(0, 0, 0); stage(0, 2, 0); stage(0, 3, 0); stage(0, 1, 0);
    stage(1, 0, 1); stage(1, 2, 1); stage(1, 3, 1);
    asm volatile("s_waitcnt vmcnt(6)" ::: "memory");
    BAR();

    auto iter = [&](int t, int c) {
        bf16x8 a[4][2], b[4][2];

        #pragma unroll
        for (int ni = 0; ni < 2; ++ni)
            #pragma unroll
            for (int s = 0; s < 2; ++s) b[ni][s] = ldb_frag(c, ni, s);
        #pragma unroll
        for (int mi = 0; mi < 4; ++mi)
            #pragma unroll
            for (int s = 0; s < 2; ++s) a[mi][s] = lda_frag(c, mi, s);
        if (t + 1 < NT) stage(t + 1, 1, c ^ 1);
        BAR();
        __builtin_amdgcn_s_setprio(1);
        #pragma unroll
        for (int mi = 0; mi < 4; ++mi)
            #pragma unroll
            for (int ni = 0; ni < 2; ++ni)
                #pragma unroll
                for (int s = 0; s < 2; ++s)
                    acc[mi][ni] = __builtin_amdgcn_mfma_f32_16x16x32_bf16(
                        a[mi][s], b[ni][s], acc[mi][ni], 0, 0, 0);
        __builtin_amdgcn_s_setprio(0);
        BAR();

        #pragma unroll
        for (int ni = 2; ni < 4; ++ni)
            #pragma unroll
            for (int s = 0; s < 2; ++s) b[ni][s] = ldb_frag(c, ni, s);
        if (t + 2 < NT) stage(t + 2, 0, c);
        BAR();
        __builtin_amdgcn_s_setprio(1);
        #pragma unroll
        for (int mi = 0; mi < 4; ++mi)
            #pragma unroll
            for (int ni = 2; ni < 4; ++ni)
                #pragma unroll
                for (int s = 0; s < 2; ++s)
                    acc[mi][ni] = __builtin_amdgcn_mfma_f32_16x16x32_bf16(
                        a[mi][s], b[ni][s], acc[mi][ni], 0, 0, 0);
        __builtin_amdgcn_s_setprio(0);
        BAR();

        #pragma unroll
        for (int mi = 0; mi < 4; ++mi)
            #pragma unroll
            for (int s = 0; s < 2; ++s) a[mi][s] = lda_frag(c, mi + 4, s);
        if (t + 2 < NT) stage(t + 2, 2, c);
        BAR();
        __builtin_amdgcn_s_setprio(1);
        #pragma unroll
        for (int mi = 0; mi < 4; ++mi)
            #pragma unroll
            for (int ni = 2; ni < 4; ++ni)
                #pragma unroll
                for (int s = 0; s < 2; ++s)
                    acc[mi + 4][ni] = __builtin_amdgcn_mfma_f32_16x16x32_bf16(
                        a[mi][s], b[ni][s], acc[mi + 4][ni], 0, 0, 0);
        __builtin_amdgcn_s_setprio(0);
        BAR();

        if (t + 2 < NT) {
            stage(t + 2, 3, c);
            asm volatile("s_waitcnt vmcnt(6)" ::: "memory");
        } else {
            asm volatile("s_waitcnt vmcnt(0)" ::: "memory");
        }
        BAR();
        __builtin_amdgcn_s_setprio(1);
        #pragma unroll
        for (int mi = 0; mi < 4; ++mi)
            #pragma unroll
            for (int ni = 0; ni < 2; ++ni)
                #pragma unroll
                for (int s = 0; s < 2; ++s)
                    acc[mi + 4][ni] = __builtin_amdgcn_mfma_f32_16x16x32_bf16(
                        a[mi][s], b[ni][s], acc[mi + 4][ni], 0, 0, 0);
        __builtin_amdgcn_s_setprio(0);
        BAR();
    };

    for (int t = 0; t < NT; t += 2) { iter(t, 0); iter(t + 1, 1); }

    #pragma unroll
    for (int mi = 0; mi < 8; ++mi) {
        #pragma unroll
        for (int ni = 0; ni < 4; ++ni) {
            const int n = bn0 + ni * 64 + wc * 16 + lr;
            const float bs = (n < 4096) ? bias0[n]
                           : (n < 5120) ? bias1[n - 4096] : bias2[n - 5120];
            const int mr = bm0 + mi * 32 + wr * 16 + kg * 4;
            #pragma unroll
            for (int r = 0; r < 4; ++r) {
                if (SPLITK) {
                    const int row = mr + r;
                    if (khalf == 0) {
                        Cf[(size_t)row * N + n] = acc[mi][ni][r] + bs;
                    } else {
                        float* P = (row < 1024) ? P0 : P1;
                        P[((size_t)(row & 1023) << 12) + n] = acc[mi][ni][r];
                    }
                } else {
                    const float val = acc[mi][ni][r] + bs;
                    if (OUT_BF16) Cb[(size_t)(mr + r) * N + n] = f2bf(val);
                    else          Cf[(size_t)(mr + r) * N + n] = val;
                }
            }
        }
    }
}

// ---------------- split-K reduce: out += partial (grid-stride) ----------------
__global__ void reduce_add(const float* __restrict__ P0, const float* __restrict__ P1,
                           float* __restrict__ out)
{
    const int n4 = M_ * D_ / 4;
    for (int i4 = blockIdx.x * blockDim.x + threadIdx.x; i4 < n4;
         i4 += gridDim.x * blockDim.x) {
        const float4 p = (i4 < (1 << 20))
            ? *(const float4*)&P0[(size_t)i4 * 4]
            : *(const float4*)&P1[(size_t)(i4 - (1 << 20)) * 4];
        float4 o = *(float4*)&out[(size_t)i4 * 4];
        o.x += p.x; o.y += p.y; o.z += p.z; o.w += p.w;
        *(float4*)&out[(size_t)i4 * 4] = o;
    }
}

// ---------------- V transpose: qkv v-cols -> [B*G][HD][S] ----------------
__global__ __launch_bounds__(256) void vtrans(
    const ushort_t* __restrict__ vb,   // qkv + 5120
    ushort_t* __restrict__ vT)
{
    __shared__ ushort_t t[32][40];
    const int s0 = blockIdx.x * 32;
    const int d0 = blockIdx.y * 32;
    const int bg = blockIdx.z;
    const int b = bg >> 3, g = bg & 7;
    const int tid = threadIdx.x;
    const int row = tid >> 3, c4 = (tid & 7) * 4;
    const us4 v = *(const us4*)&vb[(size_t)(b * S_ + s0 + row) * QN_ + g * HD_ + d0 + c4];
    t[row][c4 + 0] = v.x; t[row][c4 + 1] = v.y;
    t[row][c4 + 2] = v.z; t[row][c4 + 3] = v.w;
    __syncthreads();
    us4 o;
    o.x = t[c4 + 0][row]; o.y = t[c4 + 1][row];
    o.z = t[c4 + 2][row]; o.w = t[c4 + 3][row];
    *(us4*)&vT[(size_t)(bg * HD_ + d0 + row) * S_ + s0 + c4] = o;
}

// ---------------- MFMA attention: block = (b, h, 64 q-rows), 4 waves ----------------
__global__ __launch_bounds__(256) void attn_mfma(
    const ushort_t* __restrict__ kb,   // qkv + 4096 (rope'd K cols)
    const ushort_t* __restrict__ vT,   // [B*G][HD][S]
    ushort_t* __restrict__ qb)         // qkv (rope'd+scaled q cols), in/out
{
    __shared__ ushort_t sKV[8192];          // 16 KB staging
    __shared__ ushort_t sP[4 * 16 * 512];   // 64 KB per-wave P

    const int q0 = blockIdx.x * 64;
    const int h = blockIdx.y, b = blockIdx.z;
    const int g = h >> 2;
    const int tid = threadIdx.x;
    const int lane = tid & 63, w = tid >> 6;
    const int lr = lane & 15, kg = lane >> 4;

    bf16x8 af[4];
    {
        const ushort_t* qrow = qb + (size_t)(b * S_ + q0 + w * 16 + lr) * QN_ + h * HD_;
        #pragma unroll
        for (int c = 0; c < 4; ++c)
            af[c] = *(const bf16x8*)(qrow + c * 32 + kg * 8);
    }

    f32x4 l[8][4];
    #pragma unroll
    for (int ch = 0; ch < 8; ++ch)
        #pragma unroll
        for (int t = 0; t < 4; ++t)
            l[ch][t] = (f32x4){0.f, 0.f, 0.f, 0.f};

    // ---- QK^T ----
    const ushort_t* kbase = kb + (size_t)b * S_ * QN_ + g * HD_;
    #pragma unroll
    for (int ch = 0; ch < 8; ++ch) {
        __syncthreads();
        #pragma unroll
        for (int i = 0; i < 4; ++i) {
            const int o = w * 4096 + i * 1024;
            const int key = (o >> 8) + (lane >> 4);
            const int sl = lane & 15;
            gload_lds16(kbase + (size_t)(ch * 64 + key) * QN_ + ((sl ^ (key & 15)) * 8),
                        (char*)sKV + o);
        }
        __syncthreads();
        #pragma unroll
        for (int t = 0; t < 4; ++t) {
            const int key = t * 16 + lr;
            #pragma unroll
            for (int c = 0; c < 4; ++c) {
                const bf16x8 bf = *(const bf16x8*)((const char*)sKV + key * 256 +
                                                   (((c * 4 + kg) ^ (key & 15)) << 4));
                l[ch][t] = __builtin_amdgcn_mfma_f32_16x16x32_bf16(af[c], bf, l[ch][t], 0, 0, 0);
            }
        }
    }

    // ---- softmax ----
    float inv[4];
    #pragma unroll
    for (int r = 0; r < 4; ++r) {
        float m = -1e30f;
        #pragma unroll
        for (int ch = 0; ch < 8; ++ch)
            #pragma unroll
            for (int t = 0; t < 4; ++t)
                m = fmaxf(m, l[ch][t][r]);
        #pragma unroll
        for (int msk = 1; msk <= 8; msk <<= 1)
            m = fmaxf(m, __shfl_xor(m, msk));
        float s = 0.f;
        const int q = kg * 4 + r;
        #pragma unroll
        for (int ch = 0; ch < 8; ++ch)
            #pragma unroll
            for (int t = 0; t < 4; ++t) {
                const float p = __expf(l[ch][t][r] - m);
                s += p;
                const int gs = ch * 8 + t * 2 + (lr >> 3);
                sP[w * 8192 + q * 512 + ((gs ^ q) << 3) + (lr & 7)] = f2bf(p);
            }
        #pragma unroll
        for (int msk = 1; msk <= 8; msk <<= 1)
            s += __shfl_xor(s, msk);
        inv[r] = 1.f / s;
    }

    // ---- PV ----
    f32x4 oacc[8];
    #pragma unroll
    for (int dt = 0; dt < 8; ++dt) oacc[dt] = (f32x4){0.f, 0.f, 0.f, 0.f};

    const ushort_t* vbase = vT + (size_t)(b * G_ + g) * HD_ * S_;
    for (int ch = 0; ch < 8; ++ch) {
        __syncthreads();
        #pragma unroll
        for (int i = 0; i < 4; ++i) {
            const int o = w * 4096 + i * 1024;
            const int d = (o >> 7) + (lane >> 3);
            const int sl = lane & 7;
            gload_lds16(vbase + (size_t)d * S_ + ch * 64 + ((sl ^ (d & 7)) * 8),
                        (char*)sKV + o);
        }
        __syncthreads();
        #pragma unroll
        for (int c2 = 0; c2 < 2; ++c2) {
            const int gs = ch * 8 + c2 * 4 + kg;
            const bf16x8 ap = *(const bf16x8*)((const char*)sP + w * 16384 + lr * 1024 +
                                               ((gs ^ lr) << 4));
            #pragma unroll
            for (int dt = 0; dt < 8; ++dt) {
                const int d = dt * 16 + lr;
                const bf16x8 bv = *(const bf16x8*)((const char*)sKV + d * 128 +
                                                   (((c2 * 4 + kg) ^ (d & 7)) << 4));
                oacc[dt] = __builtin_amdgcn_mfma_f32_16x16x32_bf16(ap, bv, oacc[dt], 0, 0, 0);
            }
        }
    }

    #pragma unroll
    for (int dt = 0; dt < 8; ++dt) {
        #pragma unroll
        for (int r = 0; r < 4; ++r) {
            const int q = kg * 4 + r;
            qb[(size_t)(b * S_ + q0 + w * 16 + q) * QN_ + h * HD_ + dt * 16 + lr] =
                f2bf(oacc[dt][r] * inv[r]);
        }
    }
}

extern "C" void kernel_launch(void* const* d_in, const int* in_sizes, int n_in,
                              void* d_out, int out_size, void* d_ws, size_t ws_size,
                              hipStream_t stream)
{
    const float* x  = (const float*)d_in[0];
    const float* wq = (const float*)d_in[1];
    const float* bq = (const float*)d_in[2];
    const float* wk = (const float*)d_in[3];
    const float* bk = (const float*)d_in[4];
    const float* wv = (const float*)d_in[5];
    const float* bv = (const float*)d_in[6];
    const float* wo = (const float*)d_in[7];
    const float* bo = (const float*)d_in[8];
    float* out = (float*)d_out;

    char* ws = (char*)d_ws;
    ushort_t* xb   = (ushort_t*)(ws);                 // 16 MB: x bf16; later splitK P0
    ushort_t* Wt   = (ushort_t*)(ws + (16u << 20));   // 48 MB: wq|wk|wv; later wo rows 0-4095
    ushort_t* vT   = (ushort_t*)(ws + (48u << 20));   //  4 MB: dead wk rows after QKV GEMM
    ushort_t* qkv  = (ushort_t*)(ws + (64u << 20));   // 24 MB: [2048][6144] bf16
    float* p0      = (float*)xb;                      // 16 MB fp32 (xb dead post-QKV)
    float* p1      = (float*)(ws + (48u << 20));      // 16 MB fp32 (post-attn)
    // total 88 MB

    // weights first, x last -> QKV GEMM inputs are the freshest L3 stream
    wconv_all<<<dim3(QN_ / 32, D_ / 32), 256, 0, stream>>>(wq, wk, wv, Wt);
    xconv<<<(M_ * D_ / 8 + 255) / 256, 256, 0, stream>>>(x, xb, M_ * D_ / 8);

    // fused QKV projection + RoPE + q-scale, 128x384 tiles, full 256-block fill
    gemm_qkv<<<256, 512, 0, stream>>>(xb, Wt, bq, bk, bv, qkv);

    vtrans<<<dim3(S_ / 32, HD_ / 32, B_ * G_), 256, 0, stream>>>(qkv + 5120, vT);

    attn_mfma<<<dim3(S_ / 64, H_, B_), 256, 0, stream>>>(qkv + 4096, vT, qkv);

    // wo -> rows 0-4095 of Wt (wq part is dead now)
    wconv<<<dim3(D_ / 32, D_ / 32), 256, 0, stream>>>(wo, Wt, D_, D_);

    // O projection, split-K=2 across a full 256-block grid
    gemm8<0, 1, 0><<<256, 512, 0, stream>>>(
        qkv, QN_, Wt, D_, bo, bo, bo, out, nullptr, p0, p1, M_, D_, 2048);
    reduce_add<<<2048, 256, 0, stream>>>(p0, p1, out);
}

// Round 17
// 309.935 us; speedup vs baseline: 1.0665x; 1.0027x over previous
//
#include <hip/hip_runtime.h>
#include <math.h>

typedef unsigned short ushort_t;
typedef __attribute__((ext_vector_type(8))) short bf16x8;
typedef __attribute__((ext_vector_type(4))) float f32x4;
typedef __attribute__((ext_vector_type(4))) unsigned short us4;
typedef __attribute__((ext_vector_type(8))) unsigned short us8;

#define B_   4
#define S_   512
#define D_   4096
#define H_   32
#define G_   8
#define HD_  128
#define KV_  1024
#define M_   (B_ * S_)   // 2048
#define QN_  6144        // fused QKV column count

__device__ __forceinline__ float bf2f(ushort_t u) {
    union { unsigned u; float f; } x; x.u = ((unsigned)u) << 16; return x.f;
}
__device__ __forceinline__ ushort_t f2bf(float f) {
    union { float f; unsigned u; } x; x.f = f;
    unsigned r = x.u + 0x7fffu + ((x.u >> 16) & 1u);   // round-to-nearest-even
    return (ushort_t)(r >> 16);
}

typedef const __attribute__((address_space(1))) void* gptr_t;
typedef __attribute__((address_space(3))) void* ldsptr_t;

__device__ __forceinline__ void gload_lds16(const void* g, void* lds) {
    __builtin_amdgcn_global_load_lds((gptr_t)g, (ldsptr_t)lds, 16, 0, 0);
}

#define BAR() asm volatile("s_barrier" ::: "memory")

// ---------------- fp32 -> bf16 elementwise ----------------
__global__ void xconv(const float* __restrict__ x, ushort_t* __restrict__ xb, int n8)
{
    const int i = blockIdx.x * blockDim.x + threadIdx.x;
    if (i >= n8) return;
    const float4 a = *(const float4*)&x[(size_t)i * 8];
    const float4 b = *(const float4*)&x[(size_t)i * 8 + 4];
    us8 o;
    o[0] = f2bf(a.x); o[1] = f2bf(a.y); o[2] = f2bf(a.z); o[3] = f2bf(a.w);
    o[4] = f2bf(b.x); o[5] = f2bf(b.y); o[6] = f2bf(b.z); o[7] = f2bf(b.w);
    *(us8*)&xb[(size_t)i * 8] = o;
}

// ------- fused W transpose: {wq|wk|wv} [4096][N] fp32 -> Wt [6144][4096] bf16 -------
__global__ __launch_bounds__(256) void wconv_all(
    const float* __restrict__ wq, const float* __restrict__ wk,
    const float* __restrict__ wv, ushort_t* __restrict__ Wt)
{
    __shared__ float t[32][33];
    const int n0 = blockIdx.x * 32, k0 = blockIdx.y * 32;
    const float* W; int nsrc, N;
    if (n0 < 4096)      { W = wq; nsrc = n0;        N = 4096; }
    else if (n0 < 5120) { W = wk; nsrc = n0 - 4096; N = 1024; }
    else                { W = wv; nsrc = n0 - 5120; N = 1024; }
    const int tid = threadIdx.x;
    const int r = tid >> 3, c4 = (tid & 7) * 4;
    const float4 v = *(const float4*)&W[(size_t)(k0 + r) * N + nsrc + c4];
    t[r][c4 + 0] = v.x; t[r][c4 + 1] = v.y; t[r][c4 + 2] = v.z; t[r][c4 + 3] = v.w;
    __syncthreads();
    us4 o;
    o.x = f2bf(t[c4 + 0][r]);
    o.y = f2bf(t[c4 + 1][r]);
    o.z = f2bf(t[c4 + 2][r]);
    o.w = f2bf(t[c4 + 3][r]);
    *(us4*)&Wt[(size_t)(n0 + r) * D_ + k0 + c4] = o;
}

// ---------------- W [K][N] fp32 -> Wt [N][K] bf16 (single, for wo) ----------------
__global__ __launch_bounds__(256) void wconv(
    const float* __restrict__ W, ushort_t* __restrict__ Wt, int K, int N)
{
    __shared__ float t[32][33];
    const int n0 = blockIdx.x * 32, k0 = blockIdx.y * 32;
    const int tid = threadIdx.x;
    const int r = tid >> 3, c4 = (tid & 7) * 4;
    const float4 v = *(const float4*)&W[(size_t)(k0 + r) * N + n0 + c4];
    t[r][c4 + 0] = v.x; t[r][c4 + 1] = v.y; t[r][c4 + 2] = v.z; t[r][c4 + 3] = v.w;
    __syncthreads();
    us4 o;
    o.x = f2bf(t[c4 + 0][r]);
    o.y = f2bf(t[c4 + 1][r]);
    o.z = f2bf(t[c4 + 2][r]);
    o.w = f2bf(t[c4 + 3][r]);
    *(us4*)&Wt[(size_t)(n0 + r) * K + k0 + c4] = o;
}

// ============ QKV GEMM: 128x384 tiles -> grid 16x16 = 256 (FULL chip fill) ============
// qkv[M][6144] = xb[M][4096] @ Wt[6144][4096]^T + bias, + RoPE in epilogue.
// 8 waves (2M x 4N), per-wave C = 64x96 (4x6 frags), 48 MFMA/tile in 3 phases.
// Ledger: P1 stages B2(t+1); P2 stages A,B0(t+2); P3 stages B1(t+2)+vmcnt(6)
// (retires through B2(t+1) -> tile t+1 landed before its P1).
__global__ __launch_bounds__(512, 2) void gemm_qkv(
    const ushort_t* __restrict__ A,    // [M][4096] bf16
    const ushort_t* __restrict__ Bt,   // [6144][4096] bf16
    const float* __restrict__ bias0, const float* __restrict__ bias1,
    const float* __restrict__ bias2,
    ushort_t* __restrict__ Cb)         // [M][6144] bf16
{
    __shared__ ushort_t sA[2][128 * 64];   // 32 KiB
    __shared__ ushort_t sB[2][384 * 64];   // 96 KiB

    const int tid = threadIdx.x;
    const int lane = tid & 63, w = tid >> 6;
    const int lr = lane & 15, kg = lane >> 4;
    const int wr = w >> 2, wc = w & 3;

    const int bid = (blockIdx.x & 7) * 32 + (blockIdx.x >> 3);
    const int bx = bid & 15, by = bid >> 4;
    const int bm0 = by << 7, bn0 = bx * 384;

    const int NT = 64;
    const int lda = D_, ldb = D_, N = QN_;

    const ushort_t* gp[4][2];
    char*           lp[4][2];
    #pragma unroll
    for (int u = 0; u < 4; ++u) {
        #pragma unroll
        for (int j = 0; j < 2; ++j) {
            const int o = j * 8192 + tid * 16;
            const int row = o >> 7, slot = (o >> 4) & 7;
            if (u == 0) {
                gp[u][j] = A + (size_t)(bm0 + row) * lda + ((slot ^ (row & 7)) << 3);
                lp[u][j] = (char*)sA + j * 8192 + w * 1024;
            } else {
                const int brow = (u - 1) * 128 + row;
                gp[u][j] = Bt + (size_t)(bn0 + brow) * ldb + ((slot ^ (row & 7)) << 3);
                lp[u][j] = (char*)sB + (u - 1) * 16384 + j * 8192 + w * 1024;
            }
        }
    }
    auto stage = [&](int t, int u, int c) {
        const int coff = (u == 0) ? c * 16384 : c * 49152;
        #pragma unroll
        for (int j = 0; j < 2; ++j)
            gload_lds16(gp[u][j] + t * 64, lp[u][j] + coff);
    };
    auto lda_frag = [&](int c, int mi, int s) {
        const int row = mi * 32 + wr * 16 + lr;
        return *(const bf16x8*)((const char*)sA + c * 16384 + row * 128 +
                                (((s * 4 + kg) ^ (row & 7)) << 4));
    };
    auto ldb_frag = [&](int c, int ni, int s) {
        const int row = ni * 64 + wc * 16 + lr;
        return *(const bf16x8*)((const char*)sB + c * 49152 + row * 128 +
                                (((s * 4 + kg) ^ (row & 7)) << 4));
    };

    f32x4 acc[4][6];
    #pragma unroll
    for (int i = 0; i < 4; ++i)
        #pragma unroll
        for (int j = 0; j < 6; ++j)
            acc[i][j] = (f32x4){0.f, 0.f, 0.f, 0.f};

    stage(0, 0, 0); stage(0, 1, 0); stage(0, 2, 0); stage(0, 3, 0);
    stage(1, 0, 1); stage(1, 1, 1); stage(1, 2, 1);
    asm volatile("s_waitcnt vmcnt(6)" ::: "memory");
    BAR();

    auto iter = [&](int t, int c) {
        bf16x8 a[4][2], b[2][2];

        #pragma unroll
        for (int ni = 0; ni < 2; ++ni)
            #pragma unroll
            for (int s = 0; s < 2; ++s) b[ni][s] = ldb_frag(c, ni, s);
        #pragma unroll
        for (int mi = 0; mi < 4; ++mi)
            #pragma unroll
            for (int s = 0; s < 2; ++s) a[mi][s] = lda_frag(c, mi, s);
        if (t + 1 < NT) stage(t + 1, 3, c ^ 1);
        BAR();
        __builtin_amdgcn_s_setprio(1);
        #pragma unroll
        for (int mi = 0; mi < 4; ++mi)
            #pragma unroll
            for (int ni = 0; ni < 2; ++ni)
                #pragma unroll
                for (int s = 0; s < 2; ++s)
                    acc[mi][ni] = __builtin_amdgcn_mfma_f32_16x16x32_bf16(
                        a[mi][s], b[ni][s], acc[mi][ni], 0, 0, 0);
        __builtin_amdgcn_s_setprio(0);
        BAR();

        #pragma unroll
        for (int ni = 0; ni < 2; ++ni)
            #pragma unroll
            for (int s = 0; s < 2; ++s) b[ni][s] = ldb_frag(c, ni + 2, s);
        if (t + 2 < NT) { stage(t + 2, 0, c); stage(t + 2, 1, c); }
        BAR();
        __builtin_amdgcn_s_setprio(1);
        #pragma unroll
        for (int mi = 0; mi < 4; ++mi)
            #pragma unroll
            for (int ni = 0; ni < 2; ++ni)
                #pragma unroll
                for (int s = 0; s < 2; ++s)
                    acc[mi][ni + 2] = __builtin_amdgcn_mfma_f32_16x16x32_bf16(
                        a[mi][s], b[ni][s], acc[mi][ni + 2], 0, 0, 0);
        __builtin_amdgcn_s_setprio(0);
        BAR();

        #pragma unroll
        for (int ni = 0; ni < 2; ++ni)
            #pragma unroll
            for (int s = 0; s < 2; ++s) b[ni][s] = ldb_frag(c, ni + 4, s);
        if (t + 2 < NT) {
            stage(t + 2, 2, c);
            asm volatile("s_waitcnt vmcnt(6)" ::: "memory");
        } else {
            asm volatile("s_waitcnt vmcnt(0)" ::: "memory");
        }
        BAR();
        __builtin_amdgcn_s_setprio(1);
        #pragma unroll
        for (int mi = 0; mi < 4; ++mi)
            #pragma unroll
            for (int ni = 0; ni < 2; ++ni)
                #pragma unroll
                for (int s = 0; s < 2; ++s)
                    acc[mi][ni + 4] = __builtin_amdgcn_mfma_f32_16x16x32_bf16(
                        a[mi][s], b[ni][s], acc[mi][ni + 4], 0, 0, 0);
        __builtin_amdgcn_s_setprio(0);
        BAR();
    };

    for (int t = 0; t < NT; t += 2) { iter(t, 0); iter(t + 1, 1); }

    // ---- epilogue: bias + per-pair RoPE (q: rope*1/128, k: rope, v: plain) ----
    const int jj = wc * 16 + lr;
    const float invf = __expf(-0.1439115683121279f * (float)jj); // 10000^(-jj/64)
    #pragma unroll
    for (int mi = 0; mi < 4; ++mi) {
        const int mr = bm0 + mi * 32 + wr * 16 + kg * 4;
        #pragma unroll
        for (int r = 0; r < 4; ++r) {
            const int srow = (mr + r) & 511;
            float sn, cs;
            __sincosf((float)srow * invf, &sn, &cs);
            #pragma unroll
            for (int nip = 0; nip < 3; ++nip) {
                const int pb = bn0 + nip * 128;
                const int n_lo = pb + jj, n_hi = n_lo + 64;
                const float b_lo = (n_lo < 4096) ? bias0[n_lo]
                                 : (n_lo < 5120) ? bias1[n_lo - 4096] : bias2[n_lo - 5120];
                const float b_hi = (n_hi < 4096) ? bias0[n_hi]
                                 : (n_hi < 5120) ? bias1[n_hi - 4096] : bias2[n_hi - 5120];
                const float a_lo = acc[mi][nip * 2][r] + b_lo;
                const float a_hi = acc[mi][nip * 2 + 1][r] + b_hi;
                if (pb < 5120) {
                    const float scale = (pb < 4096) ? (1.f / 128.f) : 1.f;
                    Cb[(size_t)(mr + r) * N + n_lo] = f2bf((a_lo * cs - a_hi * sn) * scale);
                    Cb[(size_t)(mr + r) * N + n_hi] = f2bf((a_hi * cs + a_lo * sn) * scale);
                } else {
                    Cb[(size_t)(mr + r) * N + n_lo] = f2bf(a_lo);
                    Cb[(size_t)(mr + r) * N + n_hi] = f2bf(a_hi);
                }
            }
        }
    }
}

// ============ 256x256 8-phase MFMA GEMM (round-12 proven form, O-proj) ============
template<int OUT_BF16, int SPLITK, int ROPE>
__global__ __launch_bounds__(512, 2) void gemm8(
    const ushort_t* __restrict__ A, int lda,
    const ushort_t* __restrict__ Bt, int ldb,
    const float* __restrict__ bias0, const float* __restrict__ bias1,
    const float* __restrict__ bias2,
    float* __restrict__ Cf, ushort_t* __restrict__ Cb,
    float* __restrict__ P0, float* __restrict__ P1,
    int M, int N, int K)
{
    __shared__ ushort_t sA[2][256 * 64];   // 64 KiB
    __shared__ ushort_t sB[2][256 * 64];   // 64 KiB

    const int tid = threadIdx.x;
    const int lane = tid & 63, w = tid >> 6;
    const int lr = lane & 15, kg = lane >> 4;
    const int wr = w >> 2, wc = w & 3;

    const int nwg = gridDim.x;
    const int cpx = nwg >> 3;
    const int bid = (blockIdx.x & 7) * cpx + (blockIdx.x >> 3);
    int khalf = 0, tile = bid;
    if (SPLITK) { khalf = bid >> 7; tile = bid & 127; }
    const int nbx = N >> 8;
    const int bx = tile % nbx, by = tile / nbx;
    const int bm0 = by << 8, bn0 = bx << 8;
    if (SPLITK) { A += (size_t)khalf * K; Bt += (size_t)khalf * K; }

    const int NT = K >> 6;

    const ushort_t* gp[4][2];
    char*           lp[4][2];
    #pragma unroll
    for (int h = 0; h < 4; ++h) {
        const ushort_t* gb; int ld; char* sbase;
        if (h < 2) { gb = A + (size_t)bm0 * lda; ld = lda; sbase = (char*)sA; }
        else       { gb = Bt + (size_t)bn0 * ldb; ld = ldb; sbase = (char*)sB; }
        const int half = h & 1;
        #pragma unroll
        for (int j = 0; j < 2; ++j) {
            const int o = j * 8192 + tid * 16;
            const int row = half * 128 + (o >> 7);
            const int slot = (o >> 4) & 7;
            gp[h][j] = gb + (size_t)row * ld + ((slot ^ (row & 7)) << 3);
            lp[h][j] = sbase + half * 16384 + j * 8192 + w * 1024;
        }
    }
    auto stage = [&](int t, int h, int c) {
        #pragma unroll
        for (int j = 0; j < 2; ++j)
            gload_lds16(gp[h][j] + t * 64, lp[h][j] + c * 32768);
    };
    auto lda_frag = [&](int c, int mi, int s) {
        const int row = mi * 32 + wr * 16 + lr;
        return *(const bf16x8*)((const char*)sA + c * 32768 + row * 128 +
                                (((s * 4 + kg) ^ (row & 7)) << 4));
    };
    auto ldb_frag = [&](int c, int ni, int s) {
        const int row = ni * 64 + wc * 16 + lr;
        return *(const bf16x8*)((const char*)sB + c * 32768 + row * 128 +
                                (((s * 4 + kg) ^ (row & 7)) << 4));
    };

    f32x4 acc[8][4];
    #pragma unroll
    for (int i = 0; i < 8; ++i)
        #pragma unroll
        for (int j = 0; j < 4; ++j)
            acc[i][j] = (f32x4){0.f, 0.f, 0.f, 0.f};

    stage(0, 0, 0); stage(0, 2, 0); stage(0, 3, 0); stage(0, 1, 0);
    stage(1, 0, 1); stage(1, 2, 1); stage(1, 3, 1);
    asm volatile("s_waitcnt vmcnt(6)" ::: "memory");
    BAR();

    auto iter = [&](int t, int c) {
        bf16x8 a[4][2], b[4][2];

        #pragma unroll
        for (int ni = 0; ni < 2; ++ni)
            #pragma unroll
            for (int s = 0; s < 2; ++s) b[ni][s] = ldb_frag(c, ni, s);
        #pragma unroll
        for (int mi = 0; mi < 4; ++mi)
            #pragma unroll
            for (int s = 0; s < 2; ++s) a[mi][s] = lda_frag(c, mi, s);
        if (t + 1 < NT) stage(t + 1, 1, c ^ 1);
        BAR();
        __builtin_amdgcn_s_setprio(1);
        #pragma unroll
        for (int mi = 0; mi < 4; ++mi)
            #pragma unroll
            for (int ni = 0; ni < 2; ++ni)
                #pragma unroll
                for (int s = 0; s < 2; ++s)
                    acc[mi][ni] = __builtin_amdgcn_mfma_f32_16x16x32_bf16(
                        a[mi][s], b[ni][s], acc[mi][ni], 0, 0, 0);
        __builtin_amdgcn_s_setprio(0);
        BAR();

        #pragma unroll
        for (int ni = 2; ni < 4; ++ni)
            #pragma unroll
            for (int s = 0; s < 2; ++s) b[ni][s] = ldb_frag(c, ni, s);
        if (t + 2 < NT) stage(t + 2, 0, c);
        BAR();
        __builtin_amdgcn_s_setprio(1);
        #pragma unroll
        for (int mi = 0; mi < 4; ++mi)
            #pragma unroll
            for (int ni = 2; ni < 4; ++ni)
                #pragma unroll
                for (int s = 0; s < 2; ++s)
                    acc[mi][ni] = __builtin_amdgcn_mfma_f32_16x16x32_bf16(
                        a[mi][s], b[ni][s], acc[mi][ni], 0, 0, 0);
        __builtin_amdgcn_s_setprio(0);
        BAR();

        #pragma unroll
        for (int mi = 0; mi < 4; ++mi)
            #pragma unroll
            for (int s = 0; s < 2; ++s) a[mi][s] = lda_frag(c, mi + 4, s);
        if (t + 2 < NT) stage(t + 2, 2, c);
        BAR();
        __builtin_amdgcn_s_setprio(1);
        #pragma unroll
        for (int mi = 0; mi < 4; ++mi)
            #pragma unroll
            for (int ni = 2; ni < 4; ++ni)
                #pragma unroll
                for (int s = 0; s < 2; ++s)
                    acc[mi + 4][ni] = __builtin_amdgcn_mfma_f32_16x16x32_bf16(
                        a[mi][s], b[ni][s], acc[mi + 4][ni], 0, 0, 0);
        __builtin_amdgcn_s_setprio(0);
        BAR();

        if (t + 2 < NT) {
            stage(t + 2, 3, c);
            asm volatile("s_waitcnt vmcnt(6)" ::: "memory");
        } else {
            asm volatile("s_waitcnt vmcnt(0)" ::: "memory");
        }
        BAR();
        __builtin_amdgcn_s_setprio(1);
        #pragma unroll
        for (int mi = 0; mi < 4; ++mi)
            #pragma unroll
            for (int ni = 0; ni < 2; ++ni)
                #pragma unroll
                for (int s = 0; s < 2; ++s)
                    acc[mi + 4][ni] = __builtin_amdgcn_mfma_f32_16x16x32_bf16(
                        a[mi][s], b[ni][s], acc[mi + 4][ni], 0, 0, 0);
        __builtin_amdgcn_s_setprio(0);
        BAR();
    };

    for (int t = 0; t < NT; t += 2) { iter(t, 0); iter(t + 1, 1); }

    #pragma unroll
    for (int mi = 0; mi < 8; ++mi) {
        #pragma unroll
        for (int ni = 0; ni < 4; ++ni) {
            const int n = bn0 + ni * 64 + wc * 16 + lr;
            const float bs = (n < 4096) ? bias0[n]
                           : (n < 5120) ? bias1[n - 4096] : bias2[n - 5120];
            const int mr = bm0 + mi * 32 + wr * 16 + kg * 4;
            #pragma unroll
            for (int r = 0; r < 4; ++r) {
                if (SPLITK) {
                    const int row = mr + r;
                    if (khalf == 0) {
                        Cf[(size_t)row * N + n] = acc[mi][ni][r] + bs;
                    } else {
                        float* P = (row < 1024) ? P0 : P1;
                        P[((size_t)(row & 1023) << 12) + n] = acc[mi][ni][r];
                    }
                } else {
                    const float val = acc[mi][ni][r] + bs;
                    if (OUT_BF16) Cb[(size_t)(mr + r) * N + n] = f2bf(val);
                    else          Cf[(size_t)(mr + r) * N + n] = val;
                }
            }
        }
    }
}

// ---------------- split-K reduce: out += partial (grid-stride) ----------------
__global__ void reduce_add(const float* __restrict__ P0, const float* __restrict__ P1,
                           float* __restrict__ out)
{
    const int n4 = M_ * D_ / 4;
    for (int i4 = blockIdx.x * blockDim.x + threadIdx.x; i4 < n4;
         i4 += gridDim.x * blockDim.x) {
        const float4 p = (i4 < (1 << 20))
            ? *(const float4*)&P0[(size_t)i4 * 4]
            : *(const float4*)&P1[(size_t)(i4 - (1 << 20)) * 4];
        float4 o = *(float4*)&out[(size_t)i4 * 4];
        o.x += p.x; o.y += p.y; o.z += p.z; o.w += p.w;
        *(float4*)&out[(size_t)i4 * 4] = o;
    }
}

// ---------------- V transpose: qkv v-cols -> [B*G][HD][S] ----------------
__global__ __launch_bounds__(256) void vtrans(
    const ushort_t* __restrict__ vb,   // qkv + 5120
    ushort_t* __restrict__ vT)
{
    __shared__ ushort_t t[32][40];
    const int s0 = blockIdx.x * 32;
    const int d0 = blockIdx.y * 32;
    const int bg = blockIdx.z;
    const int b = bg >> 3, g = bg & 7;
    const int tid = threadIdx.x;
    const int row = tid >> 3, c4 = (tid & 7) * 4;
    const us4 v = *(const us4*)&vb[(size_t)(b * S_ + s0 + row) * QN_ + g * HD_ + d0 + c4];
    t[row][c4 + 0] = v.x; t[row][c4 + 1] = v.y;
    t[row][c4 + 2] = v.z; t[row][c4 + 3] = v.w;
    __syncthreads();
    us4 o;
    o.x = t[c4 + 0][row]; o.y = t[c4 + 1][row];
    o.z = t[c4 + 2][row]; o.w = t[c4 + 3][row];
    *(us4*)&vT[(size_t)(bg * HD_ + d0 + row) * S_ + s0 + c4] = o;
}

// ---------------- MFMA attention: block = (b, h, 64 q-rows), 4 waves ----------------
__global__ __launch_bounds__(256) void attn_mfma(
    const ushort_t* __restrict__ kb,   // qkv + 4096 (rope'd K cols)
    const ushort_t* __restrict__ vT,   // [B*G][HD][S]
    ushort_t* __restrict__ qb)         // qkv (rope'd+scaled q cols), in/out
{
    __shared__ ushort_t sKV[8192];          // 16 KB staging
    __shared__ ushort_t sP[4 * 16 * 512];   // 64 KB per-wave P

    const int q0 = blockIdx.x * 64;
    const int h = blockIdx.y, b = blockIdx.z;
    const int g = h >> 2;
    const int tid = threadIdx.x;
    const int lane = tid & 63, w = tid >> 6;
    const int lr = lane & 15, kg = lane >> 4;

    bf16x8 af[4];
    {
        const ushort_t* qrow = qb + (size_t)(b * S_ + q0 + w * 16 + lr) * QN_ + h * HD_;
        #pragma unroll
        for (int c = 0; c < 4; ++c)
            af[c] = *(const bf16x8*)(qrow + c * 32 + kg * 8);
    }

    f32x4 l[8][4];
    #pragma unroll
    for (int ch = 0; ch < 8; ++ch)
        #pragma unroll
        for (int t = 0; t < 4; ++t)
            l[ch][t] = (f32x4){0.f, 0.f, 0.f, 0.f};

    // ---- QK^T ----
    const ushort_t* kbase = kb + (size_t)b * S_ * QN_ + g * HD_;
    #pragma unroll
    for (int ch = 0; ch < 8; ++ch) {
        __syncthreads();
        #pragma unroll
        for (int i = 0; i < 4; ++i) {
            const int o = w * 4096 + i * 1024;
            const int key = (o >> 8) + (lane >> 4);
            const int sl = lane & 15;
            gload_lds16(kbase + (size_t)(ch * 64 + key) * QN_ + ((sl ^ (key & 15)) * 8),
                        (char*)sKV + o);
        }
        __syncthreads();
        #pragma unroll
        for (int t = 0; t < 4; ++t) {
            const int key = t * 16 + lr;
            #pragma unroll
            for (int c = 0; c < 4; ++c) {
                const bf16x8 bf = *(const bf16x8*)((const char*)sKV + key * 256 +
                                                   (((c * 4 + kg) ^ (key & 15)) << 4));
                l[ch][t] = __builtin_amdgcn_mfma_f32_16x16x32_bf16(af[c], bf, l[ch][t], 0, 0, 0);
            }
        }
    }

    // ---- softmax ----
    float inv[4];
    #pragma unroll
    for (int r = 0; r < 4; ++r) {
        float m = -1e30f;
        #pragma unroll
        for (int ch = 0; ch < 8; ++ch)
            #pragma unroll
            for (int t = 0; t < 4; ++t)
                m = fmaxf(m, l[ch][t][r]);
        #pragma unroll
        for (int msk = 1; msk <= 8; msk <<= 1)
            m = fmaxf(m, __shfl_xor(m, msk));
        float s = 0.f;
        const int q = kg * 4 + r;
        #pragma unroll
        for (int ch = 0; ch < 8; ++ch)
            #pragma unroll
            for (int t = 0; t < 4; ++t) {
                const float p = __expf(l[ch][t][r] - m);
                s += p;
                const int gs = ch * 8 + t * 2 + (lr >> 3);
                sP[w * 8192 + q * 512 + ((gs ^ q) << 3) + (lr & 7)] = f2bf(p);
            }
        #pragma unroll
        for (int msk = 1; msk <= 8; msk <<= 1)
            s += __shfl_xor(s, msk);
        inv[r] = 1.f / s;
    }

    // ---- PV ----
    f32x4 oacc[8];
    #pragma unroll
    for (int dt = 0; dt < 8; ++dt) oacc[dt] = (f32x4){0.f, 0.f, 0.f, 0.f};

    const ushort_t* vbase = vT + (size_t)(b * G_ + g) * HD_ * S_;
    for (int ch = 0; ch < 8; ++ch) {
        __syncthreads();
        #pragma unroll
        for (int i = 0; i < 4; ++i) {
            const int o = w * 4096 + i * 1024;
            const int d = (o >> 7) + (lane >> 3);
            const int sl = lane & 7;
            gload_lds16(vbase + (size_t)d * S_ + ch * 64 + ((sl ^ (d & 7)) * 8),
                        (char*)sKV + o);
        }
        __syncthreads();
        #pragma unroll
        for (int c2 = 0; c2 < 2; ++c2) {
            const int gs = ch * 8 + c2 * 4 + kg;
            const bf16x8 ap = *(const bf16x8*)((const char*)sP + w * 16384 + lr * 1024 +
                                               ((gs ^ lr) << 4));
            #pragma unroll
            for (int dt = 0; dt < 8; ++dt) {
                const int d = dt * 16 + lr;
                const bf16x8 bv = *(const bf16x8*)((const char*)sKV + d * 128 +
                                                   (((c2 * 4 + kg) ^ (d & 7)) << 4));
                oacc[dt] = __builtin_amdgcn_mfma_f32_16x16x32_bf16(ap, bv, oacc[dt], 0, 0, 0);
            }
        }
    }

    #pragma unroll
    for (int dt = 0; dt < 8; ++dt) {
        #pragma unroll
        for (int r = 0; r < 4; ++r) {
            const int q = kg * 4 + r;
            qb[(size_t)(b * S_ + q0 + w * 16 + q) * QN_ + h * HD_ + dt * 16 + lr] =
                f2bf(oacc[dt][r] * inv[r]);
        }
    }
}

extern "C" void kernel_launch(void* const* d_in, const int* in_sizes, int n_in,
                              void* d_out, int out_size, void* d_ws, size_t ws_size,
                              hipStream_t stream)
{
    const float* x  = (const float*)d_in[0];
    const float* wq = (const float*)d_in[1];
    const float* bq = (const float*)d_in[2];
    const float* wk = (const float*)d_in[3];
    const float* bk = (const float*)d_in[4];
    const float* wv = (const float*)d_in[5];
    const float* bv = (const float*)d_in[6];
    const float* wo = (const float*)d_in[7];
    const float* bo = (const float*)d_in[8];
    float* out = (float*)d_out;

    char* ws = (char*)d_ws;
    ushort_t* xb   = (ushort_t*)(ws);                 // 16 MB: x bf16; later splitK P0
    ushort_t* Wt   = (ushort_t*)(ws + (16u << 20));   // 48 MB: wq|wk|wv; later wo rows 0-4095
    ushort_t* vT   = (ushort_t*)(ws + (48u << 20));   //  4 MB: dead wk rows after QKV GEMM
    ushort_t* qkv  = (ushort_t*)(ws + (64u << 20));   // 24 MB: [2048][6144] bf16
    float* p0      = (float*)xb;                      // 16 MB fp32 (xb dead post-QKV)
    float* p1      = (float*)(ws + (48u << 20));      // 16 MB fp32 (post-attn)
    // total 88 MB

    // weights first, x last -> QKV GEMM inputs are the freshest L3 stream
    wconv_all<<<dim3(QN_ / 32, D_ / 32), 256, 0, stream>>>(wq, wk, wv, Wt);
    xconv<<<(M_ * D_ / 8 + 255) / 256, 256, 0, stream>>>(x, xb, M_ * D_ / 8);

    // fused QKV projection + RoPE + q-scale, 128x384 tiles, full 256-block fill
    gemm_qkv<<<256, 512, 0, stream>>>(xb, Wt, bq, bk, bv, qkv);

    vtrans<<<dim3(S_ / 32, HD_ / 32, B_ * G_), 256, 0, stream>>>(qkv + 5120, vT);

    attn_mfma<<<dim3(S_ / 64, H_, B_), 256, 0, stream>>>(qkv + 4096, vT, qkv);

    // wo -> rows 0-4095 of Wt (wq part is dead now)
    wconv<<<dim3(D_ / 32, D_ / 32), 256, 0, stream>>>(wo, Wt, D_, D_);

    // O projection, split-K=2 across a full 256-block grid
    gemm8<0, 1, 0><<<256, 512, 0, stream>>>(
        qkv, QN_, Wt, D_, bo, bo, bo, out, nullptr, p0, p1, M_, D_, 2048);
    reduce_add<<<2048, 256, 0, stream>>>(p0, p1, out);
}